// Round 8
// baseline (21.694 us; speedup 1.0000x reference)
//
#include <hip/hip_runtime.h>

// Triple softmax along keys == uniform(1/S) to ~1e-7, so
//   out[b,s,:] = ((mean_s' v[b,s',:]) @ Wv.T + bv) @ Wo.T + bo
// independent of q, k, Wq, Wk, padding_mask, s. Measured absmax 2.4e-4
// (threshold 2.34e-3) rounds 1-7.
//
// Round 8: R7 (21.5us) minus one gap. Fuse matvec2+broadcast like R6 BUT
// with grid (64 col-chunks x 4 s-chunks) = 256 blocks: R6's loss was the
// write phase starved at 64 blocks (write BW needs >=256 blocks), not the
// fusion. The 4 s-replicas recompute the same 16-column r slice (3x extra
// Wo reads = 12 MB, served by shared L3; HBM fetch unchanged) -> write
// phase gets full grid, one dispatch gap saved.
//   K1 colsum partial (512 blk, nt f4 loads)
//   K2 finalize vmean (64 blk, LDS tree)
//   K3 t = vmean@Wv.T + bv (256 blk, reg-staged x, no LDS)
//   K4 r = t@Wo.T + bo + broadcast (256 blk, full-line 64B writes)

#define BATCH 4
#define SEQ 1024
#define DIM 1024
#define D4 256            // float4 per row
#define RCH 128           // K1 row-chunks (8 rows each)

typedef float f32x4 __attribute__((ext_vector_type(4)));

// ---- K1: part[b][rc][:] = sum of 8 rows of v. grid (4,128), 256 thr ----
__global__ void __launch_bounds__(256) k1_colsum(const f32x4* __restrict__ v4,
                                                 f32x4* __restrict__ part) {
    const int b = blockIdx.x, rc = blockIdx.y, tid = threadIdx.x;
    const f32x4* p = v4 + (size_t)(b * SEQ + rc * 8) * D4 + tid;
    f32x4 s = {0.f, 0.f, 0.f, 0.f};
#pragma unroll
    for (int i = 0; i < 8; ++i) s += __builtin_nontemporal_load(p + i * D4);
    part[(size_t)(b * RCH + rc) * D4 + tid] = s;    // regular store: K2 reads it
}

// ---- K2: vmean[b][:] = (1/SEQ)*sum_rc part. grid (4,16)=64 blk, 256 thr ----
__global__ void __launch_bounds__(256) k2_final(const f32x4* __restrict__ part,
                                                f32x4* __restrict__ vmean) {
    __shared__ f32x4 sh[16][16];
    const int b = blockIdx.x, cq = blockIdx.y;
    const int c = threadIdx.x & 15, g = threadIdx.x >> 4;
    const int col = cq * 16 + c;
    const f32x4* p = part + (size_t)(b * RCH + g * 8) * D4 + col;
    f32x4 s = {0.f, 0.f, 0.f, 0.f};
#pragma unroll
    for (int i = 0; i < 8; ++i) s += p[i * D4];
    sh[g][c] = s;
    __syncthreads();
    if (threadIdx.x < 16) {
        f32x4 t = sh[0][threadIdx.x];
#pragma unroll
        for (int j = 1; j < 16; ++j) t += sh[j][threadIdx.x];
        t *= (1.0f / SEQ);
        vmean[(size_t)b * D4 + cq * 16 + threadIdx.x] = t;
    }
}

// ---- K3: t[b][n] = bv[n] + vmean[b]·Wv[n]. grid 256, 256 thr ----
// wave = one Wv row x all 4 batches; x reg-staged, no LDS, no barrier.
__global__ void __launch_bounds__(256) k3_matvec(const f32x4* __restrict__ x4,
                                                 const f32x4* __restrict__ W4,
                                                 const float* __restrict__ bias,
                                                 float* __restrict__ y) {
    const int wv = threadIdx.x >> 6, lane = threadIdx.x & 63;
    const int n = blockIdx.x * 4 + wv;
    const f32x4* wrow = W4 + (size_t)n * D4;

    f32x4 w[4], xv[4][4];
#pragma unroll
    for (int it = 0; it < 4; ++it) {
        const int col = it * 64 + lane;
        w[it] = __builtin_nontemporal_load(wrow + col);
#pragma unroll
        for (int bb = 0; bb < 4; ++bb) xv[bb][it] = x4[bb * D4 + col];
    }

    float a0 = 0.f, a1 = 0.f, a2 = 0.f, a3 = 0.f;
#pragma unroll
    for (int it = 0; it < 4; ++it) {
        a0 += w[it].x * xv[0][it].x + w[it].y * xv[0][it].y
            + w[it].z * xv[0][it].z + w[it].w * xv[0][it].w;
        a1 += w[it].x * xv[1][it].x + w[it].y * xv[1][it].y
            + w[it].z * xv[1][it].z + w[it].w * xv[1][it].w;
        a2 += w[it].x * xv[2][it].x + w[it].y * xv[2][it].y
            + w[it].z * xv[2][it].z + w[it].w * xv[2][it].w;
        a3 += w[it].x * xv[3][it].x + w[it].y * xv[3][it].y
            + w[it].z * xv[3][it].z + w[it].w * xv[3][it].w;
    }
#pragma unroll
    for (int off = 32; off > 0; off >>= 1) {
        a0 += __shfl_down(a0, off);
        a1 += __shfl_down(a1, off);
        a2 += __shfl_down(a2, off);
        a3 += __shfl_down(a3, off);
    }
    if (lane == 0) {
        const float bb = bias[n];
        y[0 * DIM + n] = a0 + bb;
        y[1 * DIM + n] = a1 + bb;
        y[2 * DIM + n] = a2 + bb;
        y[3 * DIM + n] = a3 + bb;
    }
}

// ---- K4: fused r = t@Wo.T + bo AND broadcast. grid (64,4), 256 thr ----
// Block (nb,sc): computes r[all b][nb*16..+16) (same slice for all 4 sc
// replicas -> deterministic), writes those 16 cols for s in [sc*256,+256).
// Each out-row write = one full 64B line (4 lanes x f4).
__global__ void __launch_bounds__(256) k4_out(const f32x4* __restrict__ t4,
                                              const f32x4* __restrict__ Wo4,
                                              const float* __restrict__ bo,
                                              f32x4* __restrict__ out4) {
    __shared__ f32x4 sh[4 * D4];              // staged t, 16 KB
    __shared__ alignas(16) float shr[4][16];  // r slice
    const int tid = threadIdx.x;
    const int nb  = blockIdx.x;               // 0..63 column chunk
    const int sc  = blockIdx.y;               // 0..3  s chunk
#pragma unroll
    for (int k = 0; k < 4; ++k) sh[k * D4 + tid] = t4[k * D4 + tid];
    __syncthreads();

    const int wv = tid >> 6, lane = tid & 63;
#pragma unroll
    for (int i = 0; i < 4; ++i) {
        const int nl = wv * 4 + i;            // 0..15
        const int n  = nb * 16 + nl;
        const f32x4* wrow = Wo4 + (size_t)n * D4;
        float a0 = 0.f, a1 = 0.f, a2 = 0.f, a3 = 0.f;
#pragma unroll
        for (int it = 0; it < 4; ++it) {
            const int col = it * 64 + lane;
            const f32x4 w  = wrow[col];
            const f32x4 x0 = sh[col];
            const f32x4 x1 = sh[D4 + col];
            const f32x4 x2 = sh[2 * D4 + col];
            const f32x4 x3 = sh[3 * D4 + col];
            a0 += w.x * x0.x + w.y * x0.y + w.z * x0.z + w.w * x0.w;
            a1 += w.x * x1.x + w.y * x1.y + w.z * x1.z + w.w * x1.w;
            a2 += w.x * x2.x + w.y * x2.y + w.z * x2.z + w.w * x2.w;
            a3 += w.x * x3.x + w.y * x3.y + w.z * x3.z + w.w * x3.w;
        }
#pragma unroll
        for (int off = 32; off > 0; off >>= 1) {
            a0 += __shfl_down(a0, off);
            a1 += __shfl_down(a1, off);
            a2 += __shfl_down(a2, off);
            a3 += __shfl_down(a3, off);
        }
        if (lane == 0) {
            const float bb = bo[n];
            shr[0][nl] = a0 + bb;
            shr[1][nl] = a1 + bb;
            shr[2][nl] = a2 + bb;
            shr[3][nl] = a3 + bb;
        }
    }
    __syncthreads();

    // Broadcast: thread = (row-group pg 0..63, f4 index f4i 0..3).
    const f32x4* r4 = (const f32x4*)shr;      // r4[b*4 + f4i]
    const int f4i = tid & 3, pg = tid >> 2;
    const size_t cbase = (size_t)nb * 4 + f4i;
#pragma unroll
    for (int b = 0; b < 4; ++b) {
        const f32x4 val = r4[b * 4 + f4i];
#pragma unroll
        for (int ss = 0; ss < 4; ++ss) {
            const int s = sc * 256 + ss * 64 + pg;
            __builtin_nontemporal_store(val,
                out4 + (size_t)(b * SEQ + s) * D4 + cbase);
        }
    }
}

extern "C" void kernel_launch(void* const* d_in, const int* in_sizes, int n_in,
                              void* d_out, int out_size, void* d_ws, size_t ws_size,
                              hipStream_t stream) {
    const f32x4* v4  = (const f32x4*)d_in[2];
    const f32x4* Wv4 = (const f32x4*)d_in[8];
    const float* bv  = (const float*)d_in[9];
    const f32x4* Wo4 = (const f32x4*)d_in[10];
    const float* bo  = (const float*)d_in[11];
    f32x4* out4 = (f32x4*)d_out;

    float* ws = (float*)d_ws;
    f32x4* part  = (f32x4*)ws;                        // 4*128*1024 fl = 2 MB
    float* vmean = ws + (size_t)BATCH * RCH * DIM;    // 4096 floats
    float* t     = vmean + (size_t)BATCH * DIM;       // 4096 floats

    k1_colsum<<<dim3(BATCH, RCH), 256, 0, stream>>>(v4, part);
    k2_final<<<dim3(BATCH, 16), 256, 0, stream>>>(part, (f32x4*)vmean);
    k3_matvec<<<256, 256, 0, stream>>>((const f32x4*)vmean, Wv4, bv, t);
    k4_out<<<dim3(64, 4), 256, 0, stream>>>((const f32x4*)t, Wo4, bo, out4);
}

// Round 9
// 20.579 us; speedup vs baseline: 1.0542x; 1.0542x over previous
//
#include <hip/hip_runtime.h>

// Triple softmax along keys == uniform(1/S) to ~1e-7, so
//   out[b,s,:] = ((mean_s' v[b,s',:]) @ Wv.T + bv) @ Wo.T + bo
// independent of q, k, Wq, Wk, padding_mask, s. Measured absmax 2.4e-4
// (threshold 2.34e-3) rounds 1-8.
//
// Round 9: R7 (21.5us, 5 dispatches) -> 4 dispatches by making the column
// sum SINGLE-PASS: block = (b, 8-f4-col chunk, row-half) = 256 blocks, each
// reads a 128B-wide (one L2 line per row) column slice of 512 rows and
// LDS-tree-reduces it. The half0+half1 combine + 1/SEQ scale folds into
// matvec1's register staging (+16 tiny L2 loads, no extra dispatch).
// Tail fusion stays rejected (R8: wash). Chain:
//   KA colsum single-pass (256 blk, line-aligned col slices)
//   KB t = vmean@Wv.T + bv  (256 blk, combines halves in-reg)
//   KC r = t@Wo.T + bo      (256 blk)
//   KD broadcast            (1024 blk, nt stores)

#define BATCH 4
#define SEQ 1024
#define DIM 1024
#define D4 256            // float4 per row

typedef float f32x4 __attribute__((ext_vector_type(4)));

// ---- KA: partial[half][b][col] = sum of 512 rows. grid (4,32,2), 256 thr ----
// thread = (r 0..31, c 0..7); col = cq*8+c; rows half*512 + r + 32*i.
// Per-wave access: 8 rows x 128 B contiguous = full L2 lines.
__global__ void __launch_bounds__(256) ka_colsum(const f32x4* __restrict__ v4,
                                                 f32x4* __restrict__ partial) {
    __shared__ f32x4 sh[32][8];
    const int b = blockIdx.x, cq = blockIdx.y, half = blockIdx.z;
    const int c = threadIdx.x & 7, r = threadIdx.x >> 3;
    const int col = cq * 8 + c;
    const f32x4* p = v4 + (size_t)(b * SEQ + half * 512 + r) * D4 + col;
    f32x4 s = {0.f, 0.f, 0.f, 0.f};
#pragma unroll
    for (int i = 0; i < 16; ++i)
        s += __builtin_nontemporal_load(p + (size_t)(32 * i) * D4);
    sh[r][c] = s;
    __syncthreads();
#pragma unroll
    for (int st = 16; st > 0; st >>= 1) {
        if (r < st) sh[r][c] += sh[r + st][c];
        __syncthreads();
    }
    if (r == 0)
        partial[(size_t)(half * BATCH + b) * D4 + col] = sh[0][c];
}

// ---- KB: t[b][n] = bv[n] + ((h0+h1)/SEQ)·Wv[n]. grid 256, 256 thr ----
// wave = one Wv row x all 4 batches; x combined from halves in registers.
__global__ void __launch_bounds__(256) kb_matvec1(const f32x4* __restrict__ partial,
                                                  const f32x4* __restrict__ W4,
                                                  const float* __restrict__ bias,
                                                  float* __restrict__ y) {
    const int wv = threadIdx.x >> 6, lane = threadIdx.x & 63;
    const int n = blockIdx.x * 4 + wv;
    const f32x4* wrow = W4 + (size_t)n * D4;
    const float inv = 1.0f / SEQ;

    f32x4 w[4], xv[4][4];
#pragma unroll
    for (int it = 0; it < 4; ++it) {
        const int col = it * 64 + lane;
        w[it] = __builtin_nontemporal_load(wrow + col);
#pragma unroll
        for (int bb = 0; bb < 4; ++bb)
            xv[bb][it] = (partial[(size_t)bb * D4 + col]
                        + partial[(size_t)(BATCH + bb) * D4 + col]) * inv;
    }

    float a0 = 0.f, a1 = 0.f, a2 = 0.f, a3 = 0.f;
#pragma unroll
    for (int it = 0; it < 4; ++it) {
        a0 += w[it].x * xv[0][it].x + w[it].y * xv[0][it].y
            + w[it].z * xv[0][it].z + w[it].w * xv[0][it].w;
        a1 += w[it].x * xv[1][it].x + w[it].y * xv[1][it].y
            + w[it].z * xv[1][it].z + w[it].w * xv[1][it].w;
        a2 += w[it].x * xv[2][it].x + w[it].y * xv[2][it].y
            + w[it].z * xv[2][it].z + w[it].w * xv[2][it].w;
        a3 += w[it].x * xv[3][it].x + w[it].y * xv[3][it].y
            + w[it].z * xv[3][it].z + w[it].w * xv[3][it].w;
    }
#pragma unroll
    for (int off = 32; off > 0; off >>= 1) {
        a0 += __shfl_down(a0, off);
        a1 += __shfl_down(a1, off);
        a2 += __shfl_down(a2, off);
        a3 += __shfl_down(a3, off);
    }
    if (lane == 0) {
        const float bb = bias[n];
        y[0 * DIM + n] = a0 + bb;
        y[1 * DIM + n] = a1 + bb;
        y[2 * DIM + n] = a2 + bb;
        y[3 * DIM + n] = a3 + bb;
    }
}

// ---- KC: r[b][n] = bo[n] + t[b]·Wo[n]. grid 256, 256 thr ----
__global__ void __launch_bounds__(256) kc_matvec2(const f32x4* __restrict__ x4,
                                                  const f32x4* __restrict__ W4,
                                                  const float* __restrict__ bias,
                                                  float* __restrict__ y) {
    const int wv = threadIdx.x >> 6, lane = threadIdx.x & 63;
    const int n = blockIdx.x * 4 + wv;
    const f32x4* wrow = W4 + (size_t)n * D4;

    f32x4 w[4], xv[4][4];
#pragma unroll
    for (int it = 0; it < 4; ++it) {
        const int col = it * 64 + lane;
        w[it] = __builtin_nontemporal_load(wrow + col);
#pragma unroll
        for (int bb = 0; bb < 4; ++bb) xv[bb][it] = x4[bb * D4 + col];
    }

    float a0 = 0.f, a1 = 0.f, a2 = 0.f, a3 = 0.f;
#pragma unroll
    for (int it = 0; it < 4; ++it) {
        a0 += w[it].x * xv[0][it].x + w[it].y * xv[0][it].y
            + w[it].z * xv[0][it].z + w[it].w * xv[0][it].w;
        a1 += w[it].x * xv[1][it].x + w[it].y * xv[1][it].y
            + w[it].z * xv[1][it].z + w[it].w * xv[1][it].w;
        a2 += w[it].x * xv[2][it].x + w[it].y * xv[2][it].y
            + w[it].z * xv[2][it].z + w[it].w * xv[2][it].w;
        a3 += w[it].x * xv[3][it].x + w[it].y * xv[3][it].y
            + w[it].z * xv[3][it].z + w[it].w * xv[3][it].w;
    }
#pragma unroll
    for (int off = 32; off > 0; off >>= 1) {
        a0 += __shfl_down(a0, off);
        a1 += __shfl_down(a1, off);
        a2 += __shfl_down(a2, off);
        a3 += __shfl_down(a3, off);
    }
    if (lane == 0) {
        const float bb = bias[n];
        y[0 * DIM + n] = a0 + bb;
        y[1 * DIM + n] = a1 + bb;
        y[2 * DIM + n] = a2 + bb;
        y[3 * DIM + n] = a3 + bb;
    }
}

// ---- KD: broadcast r to out. grid (4,256)=1024 blk, 256 thr; 4 s-rows ----
__global__ void __launch_bounds__(256) kd_bcast(const f32x4* __restrict__ r4,
                                                f32x4* __restrict__ out4) {
    const int b = blockIdx.x, sch = blockIdx.y, tid = threadIdx.x;
    const f32x4 val = r4[(size_t)b * D4 + tid];
    f32x4* o = out4 + (size_t)(b * SEQ + sch * 4) * D4 + tid;
#pragma unroll
    for (int k = 0; k < 4; ++k) __builtin_nontemporal_store(val, o + k * D4);
}

extern "C" void kernel_launch(void* const* d_in, const int* in_sizes, int n_in,
                              void* d_out, int out_size, void* d_ws, size_t ws_size,
                              hipStream_t stream) {
    const f32x4* v4  = (const f32x4*)d_in[2];
    const f32x4* Wv4 = (const f32x4*)d_in[8];
    const float* bv  = (const float*)d_in[9];
    const f32x4* Wo4 = (const f32x4*)d_in[10];
    const float* bo  = (const float*)d_in[11];
    f32x4* out4 = (f32x4*)d_out;

    float* ws = (float*)d_ws;
    f32x4* partial = (f32x4*)ws;                 // 2*4*1024 floats = 32 KB
    float* t = ws + 2 * BATCH * DIM;             // 4096 floats
    float* r = t + BATCH * DIM;                  // 4096 floats

    ka_colsum<<<dim3(BATCH, 32, 2), 256, 0, stream>>>(v4, partial);
    kb_matvec1<<<256, 256, 0, stream>>>(partial, Wv4, bv, t);
    kc_matvec2<<<256, 256, 0, stream>>>((const f32x4*)t, Wo4, bo, r);
    kd_bcast<<<dim3(BATCH, 256), 256, 0, stream>>>((const f32x4*)r, out4);
}